// Round 1
// 806.376 us; speedup vs baseline: 1.1167x; 1.1167x over previous
//
#include <hip/hip_runtime.h>
#include <math.h>

#define NPIX 16384

typedef __bf16 bf16x8 __attribute__((ext_vector_type(8)));
typedef float f32x4 __attribute__((ext_vector_type(4)));
typedef unsigned short u16;
typedef unsigned int u32;

__device__ __forceinline__ u16 f2bf(float f) {
    u32 u = __float_as_uint(f);
    u32 r = (u + 0x7FFFu + ((u >> 16) & 1u)) >> 16;
    return (u16)r;
}
__device__ __forceinline__ float bf2f(u32 s) { return __uint_as_float(s << 16); }
__device__ __forceinline__ u32 pk2(float a, float b) {
    return (u32)f2bf(a) | ((u32)f2bf(b) << 16);
}

// ---------------- K0w: convert weights to bf16 ----------------
__global__ __launch_bounds__(256) void k_cvtw(
    const float* __restrict__ wq, const float* __restrict__ wpw,
    const float* __restrict__ wout,
    u16* __restrict__ wq_b, u16* __restrict__ wpw_b, u16* __restrict__ wout_b)
{
    int id = (blockIdx.x * 256 + threadIdx.x) * 4;
    const float* s; u16* d; int off;
    if (id < 131072)      { s = wq;   d = wq_b;   off = id; }
    else if (id < 393216) { s = wpw;  d = wpw_b;  off = id - 131072; }
    else                  { s = wout; d = wout_b; off = id - 393216; }
    f32x4 v = *(const f32x4*)(s + off);
    uint2 u; u.x = pk2(v[0], v[1]); u.y = pk2(v[2], v[3]);
    *(uint2*)(d + off) = u;
}

// ---------------- K0: depthwise 3x3 conv + transpose to [n][c] bf16 ----------------
__global__ __launch_bounds__(256) void k_conv(
    const float* __restrict__ fmap, const float* __restrict__ wdw,
    u16* __restrict__ fmapT, u16* __restrict__ dwT)
{
    const int t = threadIdx.x;
    const int lane = t & 63, w = t >> 6;
    const int x = blockIdx.x, b = blockIdx.y;

    __shared__ u16 dst[2][128][66];   // 33,792 B -> 4 blocks/CU

    const float mLf = (lane == 0) ? 0.f : 1.f;
    const float mRf = (lane == 63) ? 0.f : 1.f;
    const float mTf = (x > 0) ? 1.f : 0.f;
    const float mBf = (x < 127) ? 1.f : 0.f;
    const int dT = (x > 0) ? -128 : 0;
    const int dB = (x < 127) ? 128 : 0;

    const size_t nbase = (size_t)b * NPIX + (size_t)x * 128;

    for (int chunk = 0; chunk < 4; ++chunk) {
        for (int g = 0; g < 4; ++g) {
            const int cl0 = w * 16 + g * 4;      // channel within chunk
            const int c0 = chunk * 64 + cl0;     // global channel
            float2 T[4], M[4], B[4];
            #pragma unroll
            for (int i = 0; i < 4; ++i) {
                const float* p = fmap + ((size_t)(b * 256 + c0 + i)) * NPIX + (size_t)x * 128;
                M[i] = ((const float2*)p)[lane];
                T[i] = ((const float2*)(p + dT))[lane];
                B[i] = ((const float2*)(p + dB))[lane];
            }
            #pragma unroll
            for (int i = 0; i < 4; ++i) {
                const float* wc = wdw + (c0 + i) * 9;  // block-uniform -> scalar loads
                float w0 = wc[0] * mTf, w1 = wc[1] * mTf, w2 = wc[2] * mTf;
                float w3 = wc[3],       w4 = wc[4],       w5 = wc[5];
                float w6 = wc[6] * mBf, w7 = wc[7] * mBf, w8 = wc[8] * mBf;
                float tL = __shfl_up(T[i].y, 1) * mLf;
                float mL_ = __shfl_up(M[i].y, 1) * mLf;
                float bL = __shfl_up(B[i].y, 1) * mLf;
                float tR = __shfl_down(T[i].x, 1) * mRf;
                float mR_ = __shfl_down(M[i].x, 1) * mRf;
                float bR = __shfl_down(B[i].x, 1) * mRf;
                float o0 = w0 * tL     + w1 * T[i].x + w2 * T[i].y
                         + w3 * mL_    + w4 * M[i].x + w5 * M[i].y
                         + w6 * bL     + w7 * B[i].x + w8 * B[i].y;
                float o1 = w0 * T[i].x + w1 * T[i].y + w2 * tR
                         + w3 * M[i].x + w4 * M[i].y + w5 * mR_
                         + w6 * B[i].x + w7 * B[i].y + w8 * bR;
                int cl = cl0 + i;
                dst[0][2 * lane][cl]     = f2bf(M[i].x);
                dst[0][2 * lane + 1][cl] = f2bf(M[i].y);
                dst[1][2 * lane][cl]     = f2bf(o0);
                dst[1][2 * lane + 1][cl] = f2bf(o1);
            }
        }
        __syncthreads();
        #pragma unroll
        for (int T2 = 0; T2 < 2; ++T2) {
            u16* gp = T2 ? dwT : fmapT;
            #pragma unroll
            for (int it = 0; it < 4; ++it) {
                int u = it * 256 + t;
                int y = u >> 3, c8 = (u & 7) * 8;
                const u16* s = &dst[T2][y][c8];
                uint4 val;
                val.x = *(const u32*)(s);
                val.y = *(const u32*)(s + 2);
                val.z = *(const u32*)(s + 4);
                val.w = *(const u32*)(s + 6);
                *(uint4*)(gp + (nbase + y) * 256 + chunk * 64 + c8) = val;
            }
        }
        __syncthreads();
    }
}

// ---------------- K2+K3 fused: kv projection + exp + context + denom ----------------
// Block = (batch b, head h, 2048-pixel slice s). Loops over 16 subtiles of 128 px.
// Per subtile: GEMM [128 px][128 ch] = dwT[px][256] @ wpw[ch][256]^T (pixels are
// MFMA A-rows so the epilogue packs 4 px into one 8B LDS write). k-half -> __expf
// -> EL[64][136]; v-half -> VL. Then ctx[e][d] += VL @ EL^T over pixels (register
// accum across subtiles); denom via ones-row MFMA on wave 0. One atomic pass/block.
__global__ __launch_bounds__(256) void k_kvctx(
    const u16* __restrict__ dwT, const u16* __restrict__ wpw,
    float* __restrict__ ctx, float* __restrict__ denom)
{
    const int t = threadIdx.x;
    const int lane = t & 63, w = t >> 6;
    const int l15 = lane & 15, quad = lane >> 4;

    // XCD-chunked swizzle (512 blocks, 8 XCDs -> 64-block contiguous work chunks)
    const int L = blockIdx.x;
    const int work = (L & 7) * 64 + (L >> 3);
    const int s = work >> 6;          // slice 0..7
    const int b = (work >> 3) & 7;    // batch
    const int h = work & 7;           // head
    const int bh = b * 8 + h;

    __shared__ __align__(16) u16 As[128 * 72];   // weights: rows 0..63 = k, 64..127 = v
    __shared__ __align__(16) u16 Bs[128 * 72];   // dwT pixel rows
    __shared__ __align__(16) u16 EL[64 * 136];   // exp(k) tile [ch][pix]
    __shared__ __align__(16) u16 VL[64 * 136];   // v tile [ch][pix]

    const int ph = (w & 1) * 64;      // pixel half owned by this wave
    const int ck = (w >> 1);          // 0 = k-channels half, 1 = v-channels half

    f32x4 ctxacc[4] = {};
    f32x4 dacc[4] = {};
    union { u16 a[8]; bf16x8 v; } uo;
    #pragma unroll
    for (int i = 0; i < 8; ++i) uo.a[i] = 0x3F80;  // bf16 1.0
    const bf16x8 ones = uo.v;

    for (int st = 0; st < 16; ++st) {
        const int n0 = s * 2048 + st * 128;
        const u16* xrow = dwT + ((size_t)b * NPIX + n0) * 256;
        f32x4 acc[4][4] = {};
        for (int kc = 0; kc < 4; ++kc) {
            __syncthreads();
            const int g = t & 7;
            #pragma unroll
            for (int p = 0; p < 4; ++p) {
                int row = (t >> 3) + 32 * p;
                int wr = (row < 64) ? (h * 64 + row) : (512 + h * 64 + (row - 64));
                *(uint4*)(As + row * 72 + g * 8) = *(const uint4*)(wpw + (size_t)wr * 256 + kc * 64 + g * 8);
                *(uint4*)(Bs + row * 72 + g * 8) = *(const uint4*)(xrow + (size_t)row * 256 + kc * 64 + g * 8);
            }
            __syncthreads();
            #pragma unroll
            for (int kk = 0; kk < 64; kk += 32) {
                bf16x8 av[4], bv[4];
                #pragma unroll
                for (int mf = 0; mf < 4; ++mf)
                    av[mf] = *(const bf16x8*)(Bs + (ph + mf * 16 + l15) * 72 + kk + quad * 8);
                #pragma unroll
                for (int nf = 0; nf < 4; ++nf)
                    bv[nf] = *(const bf16x8*)(As + (ck * 64 + nf * 16 + l15) * 72 + kk + quad * 8);
                #pragma unroll
                for (int mf = 0; mf < 4; ++mf)
                    #pragma unroll
                    for (int nf = 0; nf < 4; ++nf)
                        acc[mf][nf] = __builtin_amdgcn_mfma_f32_16x16x32_bf16(av[mf], bv[nf], acc[mf][nf], 0, 0, 0);
            }
        }
        // epilogue: acc rows = pixels, cols = channels. Pack 4 px / 8B write.
        u16* dst = ck ? VL : EL;
        #pragma unroll
        for (int nf = 0; nf < 4; ++nf) {
            const int ch = nf * 16 + l15;
            #pragma unroll
            for (int mf = 0; mf < 4; ++mf) {
                const int px = ph + mf * 16 + quad * 4;
                float v0 = acc[mf][nf][0], v1 = acc[mf][nf][1];
                float v2 = acc[mf][nf][2], v3 = acc[mf][nf][3];
                if (ck == 0) {
                    v0 = __expf(v0); v1 = __expf(v1);
                    v2 = __expf(v2); v3 = __expf(v3);
                }
                uint2 u; u.x = pk2(v0, v1); u.y = pk2(v2, v3);
                *(uint2*)(dst + ch * 136 + px) = u;
            }
        }
        __syncthreads();
        // ctx accumulation: wave w owns e-rows [w*16, w*16+16)
        #pragma unroll
        for (int kk2 = 0; kk2 < 128; kk2 += 32) {
            bf16x8 av = *(const bf16x8*)(VL + (w * 16 + l15) * 136 + kk2 + quad * 8);
            #pragma unroll
            for (int nf = 0; nf < 4; ++nf) {
                bf16x8 bv = *(const bf16x8*)(EL + (nf * 16 + l15) * 136 + kk2 + quad * 8);
                ctxacc[nf] = __builtin_amdgcn_mfma_f32_16x16x32_bf16(av, bv, ctxacc[nf], 0, 0, 0);
                if (w == 0)
                    dacc[nf] = __builtin_amdgcn_mfma_f32_16x16x32_bf16(ones, bv, dacc[nf], 0, 0, 0);
            }
        }
    }
    // finale: one atomic pass
    #pragma unroll
    for (int nf = 0; nf < 4; ++nf)
        #pragma unroll
        for (int r = 0; r < 4; ++r) {
            int e = w * 16 + quad * 4 + r;
            int d = nf * 16 + l15;
            atomicAdd(ctx + ((size_t)bh * 64 + e) * 64 + d, ctxacc[nf][r]);
        }
    if (w == 0 && quad == 0) {
        #pragma unroll
        for (int nf = 0; nf < 4; ++nf)
            atomicAdd(denom + bh * 64 + nf * 16 + l15, dacc[nf][0]);
    }
}

// ---------------- K1: q projection GEMM + fused per-(pixel,head) softmax * 1/8 ----------------
__global__ __launch_bounds__(256) void k_proj_q(
    const u16* __restrict__ fmapT, const u16* __restrict__ wq,
    u16* __restrict__ q)
{
    const int t = threadIdx.x;
    const int lane = t & 63, w = t >> 6;
    const int l15 = lane & 15, quad = lane >> 4;
    const int n0 = blockIdx.x * 128;
    const int o0 = blockIdx.y * 128;
    const int b  = blockIdx.z;
    __shared__ __align__(16) unsigned char smraw[71680];
    u16* As = (u16*)smraw;
    u16* Bs = As + 128 * 72;
    f32x4 acc[4][4] = {};
    const int mh = (w >> 1) * 64, nh = (w & 1) * 64;
    const u16* wrow = wq + (size_t)o0 * 256;
    const u16* xrow = fmapT + ((size_t)b * NPIX + n0) * 256;
    for (int kc = 0; kc < 4; ++kc) {
        __syncthreads();
        const int g = t & 7;
        #pragma unroll
        for (int p = 0; p < 4; ++p) {
            int row = (t >> 3) + 32 * p;
            *(uint4*)(As + row * 72 + g * 8) = *(const uint4*)(wrow + (size_t)row * 256 + kc * 64 + g * 8);
            *(uint4*)(Bs + row * 72 + g * 8) = *(const uint4*)(xrow + (size_t)row * 256 + kc * 64 + g * 8);
        }
        __syncthreads();
        #pragma unroll
        for (int kk = 0; kk < 64; kk += 32) {
            bf16x8 av[4], bv[4];
            #pragma unroll
            for (int mf = 0; mf < 4; ++mf)
                av[mf] = *(const bf16x8*)(As + (mh + mf * 16 + l15) * 72 + kk + quad * 8);
            #pragma unroll
            for (int nf = 0; nf < 4; ++nf)
                bv[nf] = *(const bf16x8*)(Bs + (nh + nf * 16 + l15) * 72 + kk + quad * 8);
            #pragma unroll
            for (int mf = 0; mf < 4; ++mf)
                #pragma unroll
                for (int nf = 0; nf < 4; ++nf)
                    acc[mf][nf] = __builtin_amdgcn_mfma_f32_16x16x32_bf16(av[mf], bv[nf], acc[mf][nf], 0, 0, 0);
        }
    }
    __syncthreads();
    float* ep = (float*)smraw;  // [128 pix][140] fp32 logits, transposed
    #pragma unroll
    for (int mf = 0; mf < 4; ++mf)
        #pragma unroll
        for (int nf = 0; nf < 4; ++nf)
            #pragma unroll
            for (int r = 0; r < 4; ++r) {
                int row = mh + mf * 16 + quad * 4 + r;  // local channel 0..127
                int col = nh + nf * 16 + l15;           // pixel
                ep[col * 140 + row] = acc[mf][nf][r];
            }
    __syncthreads();
    const int h0 = blockIdx.y * 2;
    for (int p = 0; p < 8; ++p) {
        int unit = p * 32 + (t >> 3);
        int pix = unit >> 1, hh = unit & 1;
        int d8 = (t & 7) * 8;
        f32x4 v0 = *(const f32x4*)(ep + pix * 140 + hh * 64 + d8);
        f32x4 v1 = *(const f32x4*)(ep + pix * 140 + hh * 64 + d8 + 4);
        float e0 = __expf(v0[0]), e1 = __expf(v0[1]), e2 = __expf(v0[2]), e3 = __expf(v0[3]);
        float e4 = __expf(v1[0]), e5 = __expf(v1[1]), e6 = __expf(v1[2]), e7 = __expf(v1[3]);
        float s = ((e0 + e1) + (e2 + e3)) + ((e4 + e5) + (e6 + e7));
        s += __shfl_xor(s, 1); s += __shfl_xor(s, 2); s += __shfl_xor(s, 4);
        float r = 0.125f / s;
        uint4 u;
        u.x = pk2(e0 * r, e1 * r); u.y = pk2(e2 * r, e3 * r);
        u.z = pk2(e4 * r, e5 * r); u.w = pk2(e6 * r, e7 * r);
        size_t off = (((size_t)b * 8 + h0 + hh) * NPIX + n0 + pix) * 64 + d8;
        *(uint4*)(q + off) = u;
    }
}

// ---------------- K4: out = (gelu(q @ ctx_norm)) @ w_out^T + b ----------------
__global__ __launch_bounds__(256) void k_attnout(
    const u16* __restrict__ q, const float* __restrict__ ctx,
    const float* __restrict__ denom, const u16* __restrict__ wout,
    const float* __restrict__ bout, float* __restrict__ out)
{
    const int t = threadIdx.x;
    const int lane = t & 63, w = t >> 6;
    const int l15 = lane & 15, quad = lane >> 4;
    const int n0 = blockIdx.x * 32;
    const int b  = blockIdx.y;
    __shared__ __align__(16) u16 tmp[32 * 520];
    __shared__ __align__(16) unsigned char R[20480];
    u16* qs = (u16*)R;            // [32][72]
    u16* cs = (u16*)(R + 4608);   // [64][72]
    u16* ws = (u16*)R;            // [256][40] (reused after head loop)
    for (int h = 0; h < 8; ++h) {
        __syncthreads();
        {
            int row = t >> 3, g = t & 7;
            *(uint4*)(qs + row * 72 + g * 8) =
                *(const uint4*)(q + (((size_t)b * 8 + h) * NPIX + n0 + row) * 64 + g * 8);
        }
        const int bh = b * 8 + h;
        #pragma unroll
        for (int p = 0; p < 4; ++p) {
            int idx = p * 256 + t;
            int e = idx >> 4, dq = (idx & 15) * 4;
            f32x4 c4 = *(const f32x4*)(ctx + ((size_t)bh * 64 + e) * 64 + dq);
            f32x4 d4 = *(const f32x4*)(denom + bh * 64 + dq);
            uint2 u;
            u.x = pk2(c4[0] / d4[0], c4[1] / d4[1]);
            u.y = pk2(c4[2] / d4[2], c4[3] / d4[3]);
            *(uint2*)(cs + e * 72 + dq) = u;
        }
        __syncthreads();
        f32x4 a1[2] = {};
        #pragma unroll
        for (int kk = 0; kk < 64; kk += 32) {
            bf16x8 av = *(const bf16x8*)(qs + ((w & 1) * 16 + l15) * 72 + kk + quad * 8);
            #pragma unroll
            for (int j = 0; j < 2; ++j) {
                int nf = (w >> 1) * 2 + j;
                bf16x8 bv = *(const bf16x8*)(cs + (nf * 16 + l15) * 72 + kk + quad * 8);
                a1[j] = __builtin_amdgcn_mfma_f32_16x16x32_bf16(av, bv, a1[j], 0, 0, 0);
            }
        }
        #pragma unroll
        for (int j = 0; j < 2; ++j)
            #pragma unroll
            for (int r = 0; r < 4; ++r) {
                int pix = (w & 1) * 16 + quad * 4 + r;
                int e = ((w >> 1) * 2 + j) * 16 + l15;
                float x = a1[j][r];
                float gel = 0.5f * x * (1.0f + erff(x * 0.70710678118654752f));
                tmp[pix * 520 + h * 64 + e] = f2bf(gel);
            }
    }
    __syncthreads();
    f32x4 acc[4][2] = {};
    for (int kc = 0; kc < 16; ++kc) {
        __syncthreads();
        #pragma unroll
        for (int p = 0; p < 4; ++p) {
            int c = (t >> 2) + 64 * p, g = t & 3;
            *(uint4*)(ws + c * 40 + g * 8) = *(const uint4*)(wout + (size_t)c * 512 + kc * 32 + g * 8);
        }
        __syncthreads();
        bf16x8 av[4], bv[2];
        #pragma unroll
        for (int mf = 0; mf < 4; ++mf)
            av[mf] = *(const bf16x8*)(ws + (w * 64 + mf * 16 + l15) * 40 + quad * 8);
        #pragma unroll
        for (int nf = 0; nf < 2; ++nf)
            bv[nf] = *(const bf16x8*)(tmp + (nf * 16 + l15) * 520 + kc * 32 + quad * 8);
        #pragma unroll
        for (int mf = 0; mf < 4; ++mf)
            #pragma unroll
            for (int nf = 0; nf < 2; ++nf)
                acc[mf][nf] = __builtin_amdgcn_mfma_f32_16x16x32_bf16(av[mf], bv[nf], acc[mf][nf], 0, 0, 0);
    }
    #pragma unroll
    for (int mf = 0; mf < 4; ++mf)
        #pragma unroll
        for (int nf = 0; nf < 2; ++nf)
            #pragma unroll
            for (int r = 0; r < 4; ++r) {
                int c = w * 64 + mf * 16 + quad * 4 + r;
                int pix = nf * 16 + l15;
                out[((size_t)b * 256 + c) * NPIX + n0 + pix] = acc[mf][nf][r] + bout[c];
            }
}

extern "C" void kernel_launch(void* const* d_in, const int* in_sizes, int n_in,
                              void* d_out, int out_size, void* d_ws, size_t ws_size,
                              hipStream_t stream)
{
    const float* fmap  = (const float*)d_in[0];
    const float* w_q   = (const float*)d_in[1];
    const float* w_dw  = (const float*)d_in[2];
    const float* w_pw  = (const float*)d_in[3];
    const float* w_out = (const float*)d_in[4];
    const float* b_out = (const float*)d_in[5];
    float* out = (float*)d_out;
    char* ws = (char*)d_ws;

    u16* dwT     = (u16*)(ws);                  // 67,108,864 B  [8][16384][256]
    u16* fmapT   = (u16*)(ws + 67108864);       // 67,108,864 B
    u16* q       = (u16*)(ws + 134217728);      // 134,217,728 B (E/V no longer materialized)
    float* ctx   = (float*)(ws + 402653184);    // 1,048,576 B  [64][64][64]
    float* denom = (float*)(ws + 403701760);    // 16,384 B
    u16* wq_b    = (u16*)(ws + 403718144);      // 262,144 B
    u16* wpw_b   = (u16*)(ws + 403980288);      // 524,288 B
    u16* wout_b  = (u16*)(ws + 404504576);      // 262,144 B
    // total workspace: 404,766,720 B

    hipMemsetAsync(ws + 402653184, 0, 1048576 + 16384, stream);
    k_cvtw<<<512, 256, 0, stream>>>(w_q, w_pw, w_out, wq_b, wpw_b, wout_b);
    k_conv<<<dim3(128, 8), 256, 0, stream>>>(fmap, w_dw, fmapT, dwT);
    k_kvctx<<<512, 256, 0, stream>>>(dwT, wpw_b, ctx, denom);
    k_proj_q<<<dim3(128, 4, 8), 256, 0, stream>>>(fmapT, wq_b, q);
    k_attnout<<<dim3(512, 8), 256, 0, stream>>>(q, ctx, denom, wout_b, b_out, out);
}

// Round 2
// 782.284 us; speedup vs baseline: 1.1511x; 1.0308x over previous
//
#include <hip/hip_runtime.h>
#include <math.h>

#define NPIX 16384

typedef __bf16 bf16x8 __attribute__((ext_vector_type(8)));
typedef float f32x4 __attribute__((ext_vector_type(4)));
typedef unsigned short u16;
typedef unsigned int u32;

__device__ __forceinline__ u16 f2bf(float f) {
    u32 u = __float_as_uint(f);
    u32 r = (u + 0x7FFFu + ((u >> 16) & 1u)) >> 16;
    return (u16)r;
}
__device__ __forceinline__ float bf2f(u32 s) { return __uint_as_float(s << 16); }
__device__ __forceinline__ u32 pk2(float a, float b) {
    return (u32)f2bf(a) | ((u32)f2bf(b) << 16);
}

// ---------------- K0w: convert weights to bf16 ----------------
__global__ __launch_bounds__(256) void k_cvtw(
    const float* __restrict__ wq, const float* __restrict__ wpw,
    const float* __restrict__ wout,
    u16* __restrict__ wq_b, u16* __restrict__ wpw_b, u16* __restrict__ wout_b)
{
    int id = (blockIdx.x * 256 + threadIdx.x) * 4;
    const float* s; u16* d; int off;
    if (id < 131072)      { s = wq;   d = wq_b;   off = id; }
    else if (id < 393216) { s = wpw;  d = wpw_b;  off = id - 131072; }
    else                  { s = wout; d = wout_b; off = id - 393216; }
    f32x4 v = *(const f32x4*)(s + off);
    uint2 u; u.x = pk2(v[0], v[1]); u.y = pk2(v[2], v[3]);
    *(uint2*)(d + off) = u;
}

// ---------------- K0: depthwise 3x3 conv + transpose to [n][c] bf16 ----------------
__global__ __launch_bounds__(256) void k_conv(
    const float* __restrict__ fmap, const float* __restrict__ wdw,
    u16* __restrict__ fmapT, u16* __restrict__ dwT)
{
    const int t = threadIdx.x;
    const int lane = t & 63, w = t >> 6;
    const int x = blockIdx.x, b = blockIdx.y;

    __shared__ u16 dst[2][128][66];   // 33,792 B -> 4 blocks/CU

    const float mLf = (lane == 0) ? 0.f : 1.f;
    const float mRf = (lane == 63) ? 0.f : 1.f;
    const float mTf = (x > 0) ? 1.f : 0.f;
    const float mBf = (x < 127) ? 1.f : 0.f;
    const int dT = (x > 0) ? -128 : 0;
    const int dB = (x < 127) ? 128 : 0;

    const size_t nbase = (size_t)b * NPIX + (size_t)x * 128;

    for (int chunk = 0; chunk < 4; ++chunk) {
        for (int g = 0; g < 4; ++g) {
            const int cl0 = w * 16 + g * 4;      // channel within chunk
            const int c0 = chunk * 64 + cl0;     // global channel
            float2 T[4], M[4], B[4];
            #pragma unroll
            for (int i = 0; i < 4; ++i) {
                const float* p = fmap + ((size_t)(b * 256 + c0 + i)) * NPIX + (size_t)x * 128;
                M[i] = ((const float2*)p)[lane];
                T[i] = ((const float2*)(p + dT))[lane];
                B[i] = ((const float2*)(p + dB))[lane];
            }
            #pragma unroll
            for (int i = 0; i < 4; ++i) {
                const float* wc = wdw + (c0 + i) * 9;  // block-uniform -> scalar loads
                float w0 = wc[0] * mTf, w1 = wc[1] * mTf, w2 = wc[2] * mTf;
                float w3 = wc[3],       w4 = wc[4],       w5 = wc[5];
                float w6 = wc[6] * mBf, w7 = wc[7] * mBf, w8 = wc[8] * mBf;
                float tL = __shfl_up(T[i].y, 1) * mLf;
                float mL_ = __shfl_up(M[i].y, 1) * mLf;
                float bL = __shfl_up(B[i].y, 1) * mLf;
                float tR = __shfl_down(T[i].x, 1) * mRf;
                float mR_ = __shfl_down(M[i].x, 1) * mRf;
                float bR = __shfl_down(B[i].x, 1) * mRf;
                float o0 = w0 * tL     + w1 * T[i].x + w2 * T[i].y
                         + w3 * mL_    + w4 * M[i].x + w5 * M[i].y
                         + w6 * bL     + w7 * B[i].x + w8 * B[i].y;
                float o1 = w0 * T[i].x + w1 * T[i].y + w2 * tR
                         + w3 * M[i].x + w4 * M[i].y + w5 * mR_
                         + w6 * B[i].x + w7 * B[i].y + w8 * bR;
                int cl = cl0 + i;
                dst[0][2 * lane][cl]     = f2bf(M[i].x);
                dst[0][2 * lane + 1][cl] = f2bf(M[i].y);
                dst[1][2 * lane][cl]     = f2bf(o0);
                dst[1][2 * lane + 1][cl] = f2bf(o1);
            }
        }
        __syncthreads();
        #pragma unroll
        for (int T2 = 0; T2 < 2; ++T2) {
            u16* gp = T2 ? dwT : fmapT;
            #pragma unroll
            for (int it = 0; it < 4; ++it) {
                int u = it * 256 + t;
                int y = u >> 3, c8 = (u & 7) * 8;
                const u16* s = &dst[T2][y][c8];
                uint4 val;
                val.x = *(const u32*)(s);
                val.y = *(const u32*)(s + 2);
                val.z = *(const u32*)(s + 4);
                val.w = *(const u32*)(s + 6);
                *(uint4*)(gp + (nbase + y) * 256 + chunk * 64 + c8) = val;
            }
        }
        __syncthreads();
    }
}

// ---------------- K2+K3 fused: kv projection + exp + context + denom ----------------
// Block = (batch b, head h, 1024-pixel slice s). 8 subtiles of 128 px.
// Per subtile: GEMM [128 px][128 ch] = dwT[px][256] @ wpw[ch][256]^T; k-half
// -> __expf -> EL; v-half -> VL. EL/VL ALIAS As/Bs (dead after GEMM) so
// LDS = 36,864 B. Denominator comes from acc registers in the epilogue
// (quad-shfl reduce, register-accumulated) instead of a ones-row MFMA.
// __launch_bounds__(256,3): VGPR <= 170 -> 3 waves/SIMD -> 3 blocks/CU.
__global__ __launch_bounds__(256, 3) void k_kvctx(
    const u16* __restrict__ dwT, const u16* __restrict__ wpw,
    float* __restrict__ ctx, float* __restrict__ denom)
{
    const int t = threadIdx.x;
    const int lane = t & 63, w = t >> 6;
    const int l15 = lane & 15, quad = lane >> 4;

    // XCD-chunked swizzle (1024 blocks, 8 XCDs -> 128-block contiguous chunks)
    const int L = blockIdx.x;
    const int work = (L & 7) * 128 + (L >> 3);
    const int s = work >> 6;          // slice 0..15
    const int b = (work >> 3) & 7;    // batch
    const int h = work & 7;           // head
    const int bh = b * 8 + h;

    __shared__ __align__(16) u16 As[128 * 72];   // weights; aliased as EL after GEMM
    __shared__ __align__(16) u16 Bs[128 * 72];   // dwT pixels; aliased as VL
    u16* EL = As;   // [64][136] exp(k) tile [ch][pix]  (64*136 = 8704 <= 9216)
    u16* VL = Bs;   // [64][136] v tile

    const int ph = (w & 1) * 64;      // pixel half owned by this wave
    const int ck = (w >> 1);          // 0 = k-channels half, 1 = v-channels half

    f32x4 ctxacc[4] = {};
    float dpart[4] = {0.f, 0.f, 0.f, 0.f};

    for (int st = 0; st < 8; ++st) {
        const int n0 = s * 1024 + st * 128;
        const u16* xrow = dwT + ((size_t)b * NPIX + n0) * 256;
        f32x4 acc[4][4] = {};
        for (int kc = 0; kc < 4; ++kc) {
            __syncthreads();
            const int g = t & 7;
            #pragma unroll
            for (int p = 0; p < 4; ++p) {
                int row = (t >> 3) + 32 * p;
                int wr = (row < 64) ? (h * 64 + row) : (512 + h * 64 + (row - 64));
                *(uint4*)(As + row * 72 + g * 8) = *(const uint4*)(wpw + (size_t)wr * 256 + kc * 64 + g * 8);
                *(uint4*)(Bs + row * 72 + g * 8) = *(const uint4*)(xrow + (size_t)row * 256 + kc * 64 + g * 8);
            }
            __syncthreads();
            #pragma unroll
            for (int kk = 0; kk < 64; kk += 32) {
                bf16x8 av[4], bv[4];
                #pragma unroll
                for (int mf = 0; mf < 4; ++mf)
                    av[mf] = *(const bf16x8*)(Bs + (ph + mf * 16 + l15) * 72 + kk + quad * 8);
                #pragma unroll
                for (int nf = 0; nf < 4; ++nf)
                    bv[nf] = *(const bf16x8*)(As + (ck * 64 + nf * 16 + l15) * 72 + kk + quad * 8);
                #pragma unroll
                for (int mf = 0; mf < 4; ++mf)
                    #pragma unroll
                    for (int nf = 0; nf < 4; ++nf)
                        acc[mf][nf] = __builtin_amdgcn_mfma_f32_16x16x32_bf16(av[mf], bv[nf], acc[mf][nf], 0, 0, 0);
            }
        }
        __syncthreads();   // As/Bs GEMM reads complete before aliased EL/VL writes
        // epilogue: acc rows = pixels, cols = channels. Pack 4 px / 8B write.
        u16* dst = ck ? VL : EL;
        #pragma unroll
        for (int nf = 0; nf < 4; ++nf) {
            const int ch = nf * 16 + l15;
            float colsum = 0.f;
            #pragma unroll
            for (int mf = 0; mf < 4; ++mf) {
                const int px = ph + mf * 16 + quad * 4;
                float v0 = acc[mf][nf][0], v1 = acc[mf][nf][1];
                float v2 = acc[mf][nf][2], v3 = acc[mf][nf][3];
                if (ck == 0) {
                    v0 = __expf(v0); v1 = __expf(v1);
                    v2 = __expf(v2); v3 = __expf(v3);
                    colsum += (v0 + v1) + (v2 + v3);
                }
                uint2 u; u.x = pk2(v0, v1); u.y = pk2(v2, v3);
                *(uint2*)(dst + ch * 136 + px) = u;
            }
            if (ck == 0) {
                // reduce over the 4 quads (lanes l15, l15+16, l15+32, l15+48)
                colsum += __shfl_xor(colsum, 16);
                colsum += __shfl_xor(colsum, 32);
                dpart[nf] += colsum;
            }
        }
        __syncthreads();
        // ctx accumulation: wave w owns e-rows [w*16, w*16+16)
        #pragma unroll
        for (int kk2 = 0; kk2 < 128; kk2 += 32) {
            bf16x8 av = *(const bf16x8*)(VL + (w * 16 + l15) * 136 + kk2 + quad * 8);
            #pragma unroll
            for (int nf = 0; nf < 4; ++nf) {
                bf16x8 bv = *(const bf16x8*)(EL + (nf * 16 + l15) * 136 + kk2 + quad * 8);
                ctxacc[nf] = __builtin_amdgcn_mfma_f32_16x16x32_bf16(av, bv, ctxacc[nf], 0, 0, 0);
            }
        }
    }
    // finale: one atomic pass
    #pragma unroll
    for (int nf = 0; nf < 4; ++nf)
        #pragma unroll
        for (int r = 0; r < 4; ++r) {
            int e = w * 16 + quad * 4 + r;
            int d = nf * 16 + l15;
            atomicAdd(ctx + ((size_t)bh * 64 + e) * 64 + d, ctxacc[nf][r]);
        }
    if (ck == 0 && quad == 0) {
        #pragma unroll
        for (int nf = 0; nf < 4; ++nf)
            atomicAdd(denom + bh * 64 + nf * 16 + l15, dpart[nf]);
    }
}

// ---------------- K1: q projection GEMM + fused per-(pixel,head) softmax * 1/8 ----------------
__global__ __launch_bounds__(256) void k_proj_q(
    const u16* __restrict__ fmapT, const u16* __restrict__ wq,
    u16* __restrict__ q)
{
    const int t = threadIdx.x;
    const int lane = t & 63, w = t >> 6;
    const int l15 = lane & 15, quad = lane >> 4;
    const int n0 = blockIdx.x * 128;
    const int o0 = blockIdx.y * 128;
    const int b  = blockIdx.z;
    __shared__ __align__(16) unsigned char smraw[71680];
    u16* As = (u16*)smraw;
    u16* Bs = As + 128 * 72;
    f32x4 acc[4][4] = {};
    const int mh = (w >> 1) * 64, nh = (w & 1) * 64;
    const u16* wrow = wq + (size_t)o0 * 256;
    const u16* xrow = fmapT + ((size_t)b * NPIX + n0) * 256;
    for (int kc = 0; kc < 4; ++kc) {
        __syncthreads();
        const int g = t & 7;
        #pragma unroll
        for (int p = 0; p < 4; ++p) {
            int row = (t >> 3) + 32 * p;
            *(uint4*)(As + row * 72 + g * 8) = *(const uint4*)(wrow + (size_t)row * 256 + kc * 64 + g * 8);
            *(uint4*)(Bs + row * 72 + g * 8) = *(const uint4*)(xrow + (size_t)row * 256 + kc * 64 + g * 8);
        }
        __syncthreads();
        #pragma unroll
        for (int kk = 0; kk < 64; kk += 32) {
            bf16x8 av[4], bv[4];
            #pragma unroll
            for (int mf = 0; mf < 4; ++mf)
                av[mf] = *(const bf16x8*)(As + (mh + mf * 16 + l15) * 72 + kk + quad * 8);
            #pragma unroll
            for (int nf = 0; nf < 4; ++nf)
                bv[nf] = *(const bf16x8*)(Bs + (nh + nf * 16 + l15) * 72 + kk + quad * 8);
            #pragma unroll
            for (int mf = 0; mf < 4; ++mf)
                #pragma unroll
                for (int nf = 0; nf < 4; ++nf)
                    acc[mf][nf] = __builtin_amdgcn_mfma_f32_16x16x32_bf16(av[mf], bv[nf], acc[mf][nf], 0, 0, 0);
        }
    }
    __syncthreads();
    float* ep = (float*)smraw;  // [128 pix][140] fp32 logits, transposed
    #pragma unroll
    for (int mf = 0; mf < 4; ++mf)
        #pragma unroll
        for (int nf = 0; nf < 4; ++nf)
            #pragma unroll
            for (int r = 0; r < 4; ++r) {
                int row = mh + mf * 16 + quad * 4 + r;  // local channel 0..127
                int col = nh + nf * 16 + l15;           // pixel
                ep[col * 140 + row] = acc[mf][nf][r];
            }
    __syncthreads();
    const int h0 = blockIdx.y * 2;
    for (int p = 0; p < 8; ++p) {
        int unit = p * 32 + (t >> 3);
        int pix = unit >> 1, hh = unit & 1;
        int d8 = (t & 7) * 8;
        f32x4 v0 = *(const f32x4*)(ep + pix * 140 + hh * 64 + d8);
        f32x4 v1 = *(const f32x4*)(ep + pix * 140 + hh * 64 + d8 + 4);
        float e0 = __expf(v0[0]), e1 = __expf(v0[1]), e2 = __expf(v0[2]), e3 = __expf(v0[3]);
        float e4 = __expf(v1[0]), e5 = __expf(v1[1]), e6 = __expf(v1[2]), e7 = __expf(v1[3]);
        float s = ((e0 + e1) + (e2 + e3)) + ((e4 + e5) + (e6 + e7));
        s += __shfl_xor(s, 1); s += __shfl_xor(s, 2); s += __shfl_xor(s, 4);
        float r = 0.125f / s;
        uint4 u;
        u.x = pk2(e0 * r, e1 * r); u.y = pk2(e2 * r, e3 * r);
        u.z = pk2(e4 * r, e5 * r); u.w = pk2(e6 * r, e7 * r);
        size_t off = (((size_t)b * 8 + h0 + hh) * NPIX + n0 + pix) * 64 + d8;
        *(uint4*)(q + off) = u;
    }
}

// ---------------- K4: out = (gelu(q @ ctx_norm)) @ w_out^T + b ----------------
__global__ __launch_bounds__(256) void k_attnout(
    const u16* __restrict__ q, const float* __restrict__ ctx,
    const float* __restrict__ denom, const u16* __restrict__ wout,
    const float* __restrict__ bout, float* __restrict__ out)
{
    const int t = threadIdx.x;
    const int lane = t & 63, w = t >> 6;
    const int l15 = lane & 15, quad = lane >> 4;
    const int n0 = blockIdx.x * 32;
    const int b  = blockIdx.y;
    __shared__ __align__(16) u16 tmp[32 * 520];
    __shared__ __align__(16) unsigned char R[20480];
    u16* qs = (u16*)R;            // [32][72]
    u16* cs = (u16*)(R + 4608);   // [64][72]
    u16* ws = (u16*)R;            // [256][40] (reused after head loop)
    for (int h = 0; h < 8; ++h) {
        __syncthreads();
        {
            int row = t >> 3, g = t & 7;
            *(uint4*)(qs + row * 72 + g * 8) =
                *(const uint4*)(q + (((size_t)b * 8 + h) * NPIX + n0 + row) * 64 + g * 8);
        }
        const int bh = b * 8 + h;
        #pragma unroll
        for (int p = 0; p < 4; ++p) {
            int idx = p * 256 + t;
            int e = idx >> 4, dq = (idx & 15) * 4;
            f32x4 c4 = *(const f32x4*)(ctx + ((size_t)bh * 64 + e) * 64 + dq);
            f32x4 d4 = *(const f32x4*)(denom + bh * 64 + dq);
            uint2 u;
            u.x = pk2(c4[0] / d4[0], c4[1] / d4[1]);
            u.y = pk2(c4[2] / d4[2], c4[3] / d4[3]);
            *(uint2*)(cs + e * 72 + dq) = u;
        }
        __syncthreads();
        f32x4 a1[2] = {};
        #pragma unroll
        for (int kk = 0; kk < 64; kk += 32) {
            bf16x8 av = *(const bf16x8*)(qs + ((w & 1) * 16 + l15) * 72 + kk + quad * 8);
            #pragma unroll
            for (int j = 0; j < 2; ++j) {
                int nf = (w >> 1) * 2 + j;
                bf16x8 bv = *(const bf16x8*)(cs + (nf * 16 + l15) * 72 + kk + quad * 8);
                a1[j] = __builtin_amdgcn_mfma_f32_16x16x32_bf16(av, bv, a1[j], 0, 0, 0);
            }
        }
        #pragma unroll
        for (int j = 0; j < 2; ++j)
            #pragma unroll
            for (int r = 0; r < 4; ++r) {
                int pix = (w & 1) * 16 + quad * 4 + r;
                int e = ((w >> 1) * 2 + j) * 16 + l15;
                float x = a1[j][r];
                float gel = 0.5f * x * (1.0f + erff(x * 0.70710678118654752f));
                tmp[pix * 520 + h * 64 + e] = f2bf(gel);
            }
    }
    __syncthreads();
    f32x4 acc[4][2] = {};
    for (int kc = 0; kc < 16; ++kc) {
        __syncthreads();
        #pragma unroll
        for (int p = 0; p < 4; ++p) {
            int c = (t >> 2) + 64 * p, g = t & 3;
            *(uint4*)(ws + c * 40 + g * 8) = *(const uint4*)(wout + (size_t)c * 512 + kc * 32 + g * 8);
        }
        __syncthreads();
        bf16x8 av[4], bv[2];
        #pragma unroll
        for (int mf = 0; mf < 4; ++mf)
            av[mf] = *(const bf16x8*)(ws + (w * 64 + mf * 16 + l15) * 40 + quad * 8);
        #pragma unroll
        for (int nf = 0; nf < 2; ++nf)
            bv[nf] = *(const bf16x8*)(tmp + (nf * 16 + l15) * 520 + kc * 32 + quad * 8);
        #pragma unroll
        for (int mf = 0; mf < 4; ++mf)
            #pragma unroll
            for (int nf = 0; nf < 2; ++nf)
                acc[mf][nf] = __builtin_amdgcn_mfma_f32_16x16x32_bf16(av[mf], bv[nf], acc[mf][nf], 0, 0, 0);
    }
    #pragma unroll
    for (int mf = 0; mf < 4; ++mf)
        #pragma unroll
        for (int nf = 0; nf < 2; ++nf)
            #pragma unroll
            for (int r = 0; r < 4; ++r) {
                int c = w * 64 + mf * 16 + quad * 4 + r;
                int pix = nf * 16 + l15;
                out[((size_t)b * 256 + c) * NPIX + n0 + pix] = acc[mf][nf][r] + bout[c];
            }
}

extern "C" void kernel_launch(void* const* d_in, const int* in_sizes, int n_in,
                              void* d_out, int out_size, void* d_ws, size_t ws_size,
                              hipStream_t stream)
{
    const float* fmap  = (const float*)d_in[0];
    const float* w_q   = (const float*)d_in[1];
    const float* w_dw  = (const float*)d_in[2];
    const float* w_pw  = (const float*)d_in[3];
    const float* w_out = (const float*)d_in[4];
    const float* b_out = (const float*)d_in[5];
    float* out = (float*)d_out;
    char* ws = (char*)d_ws;

    u16* dwT     = (u16*)(ws);                  // 67,108,864 B  [8][16384][256]
    u16* fmapT   = (u16*)(ws + 67108864);       // 67,108,864 B
    u16* q       = (u16*)(ws + 134217728);      // 134,217,728 B
    float* ctx   = (float*)(ws + 402653184);    // 1,048,576 B  [64][64][64]
    float* denom = (float*)(ws + 403701760);    // 16,384 B
    u16* wq_b    = (u16*)(ws + 403718144);      // 262,144 B
    u16* wpw_b   = (u16*)(ws + 403980288);      // 524,288 B
    u16* wout_b  = (u16*)(ws + 404504576);      // 262,144 B
    // total workspace: 404,766,720 B

    hipMemsetAsync(ws + 402653184, 0, 1048576 + 16384, stream);
    k_cvtw<<<512, 256, 0, stream>>>(w_q, w_pw, w_out, wq_b, wpw_b, wout_b);
    k_conv<<<dim3(128, 8), 256, 0, stream>>>(fmap, w_dw, fmapT, dwT);
    k_kvctx<<<1024, 256, 0, stream>>>(dwT, wpw_b, ctx, denom);
    k_proj_q<<<dim3(128, 4, 8), 256, 0, stream>>>(fmapT, wq_b, q);
    k_attnout<<<dim3(512, 8), 256, 0, stream>>>(q, ctx, denom, wout_b, b_out, out);
}

// Round 3
// 735.314 us; speedup vs baseline: 1.2246x; 1.0639x over previous
//
#include <hip/hip_runtime.h>
#include <math.h>

#define NPIX 16384

typedef __bf16 bf16x8 __attribute__((ext_vector_type(8)));
typedef float f32x4 __attribute__((ext_vector_type(4)));
typedef unsigned short u16;
typedef unsigned int u32;

__device__ __forceinline__ u16 f2bf(float f) {
    u32 u = __float_as_uint(f);
    u32 r = (u + 0x7FFFu + ((u >> 16) & 1u)) >> 16;
    return (u16)r;
}
__device__ __forceinline__ float bf2f(u32 s) { return __uint_as_float(s << 16); }
__device__ __forceinline__ u32 pk2(float a, float b) {
    return (u32)f2bf(a) | ((u32)f2bf(b) << 16);
}

// ---------------- K0w: convert weights to bf16 ----------------
__global__ __launch_bounds__(256) void k_cvtw(
    const float* __restrict__ wq, const float* __restrict__ wpw,
    const float* __restrict__ wout,
    u16* __restrict__ wq_b, u16* __restrict__ wpw_b, u16* __restrict__ wout_b)
{
    int id = (blockIdx.x * 256 + threadIdx.x) * 4;
    const float* s; u16* d; int off;
    if (id < 131072)      { s = wq;   d = wq_b;   off = id; }
    else if (id < 393216) { s = wpw;  d = wpw_b;  off = id - 131072; }
    else                  { s = wout; d = wout_b; off = id - 393216; }
    f32x4 v = *(const f32x4*)(s + off);
    uint2 u; u.x = pk2(v[0], v[1]); u.y = pk2(v[2], v[3]);
    *(uint2*)(d + off) = u;
}

// ---------------- K0: depthwise 3x3 conv + transpose to [n][c] bf16 ----------------
__global__ __launch_bounds__(256) void k_conv(
    const float* __restrict__ fmap, const float* __restrict__ wdw,
    u16* __restrict__ fmapT, u16* __restrict__ dwT)
{
    const int t = threadIdx.x;
    const int lane = t & 63, w = t >> 6;
    const int x = blockIdx.x, b = blockIdx.y;

    __shared__ u16 dst[2][128][66];   // 33,792 B -> 4 blocks/CU

    const float mLf = (lane == 0) ? 0.f : 1.f;
    const float mRf = (lane == 63) ? 0.f : 1.f;
    const float mTf = (x > 0) ? 1.f : 0.f;
    const float mBf = (x < 127) ? 1.f : 0.f;
    const int dT = (x > 0) ? -128 : 0;
    const int dB = (x < 127) ? 128 : 0;

    const size_t nbase = (size_t)b * NPIX + (size_t)x * 128;

    for (int chunk = 0; chunk < 4; ++chunk) {
        for (int g = 0; g < 4; ++g) {
            const int cl0 = w * 16 + g * 4;      // channel within chunk
            const int c0 = chunk * 64 + cl0;     // global channel
            float2 T[4], M[4], B[4];
            #pragma unroll
            for (int i = 0; i < 4; ++i) {
                const float* p = fmap + ((size_t)(b * 256 + c0 + i)) * NPIX + (size_t)x * 128;
                M[i] = ((const float2*)p)[lane];
                T[i] = ((const float2*)(p + dT))[lane];
                B[i] = ((const float2*)(p + dB))[lane];
            }
            #pragma unroll
            for (int i = 0; i < 4; ++i) {
                const float* wc = wdw + (c0 + i) * 9;  // block-uniform -> scalar loads
                float w0 = wc[0] * mTf, w1 = wc[1] * mTf, w2 = wc[2] * mTf;
                float w3 = wc[3],       w4 = wc[4],       w5 = wc[5];
                float w6 = wc[6] * mBf, w7 = wc[7] * mBf, w8 = wc[8] * mBf;
                float tL = __shfl_up(T[i].y, 1) * mLf;
                float mL_ = __shfl_up(M[i].y, 1) * mLf;
                float bL = __shfl_up(B[i].y, 1) * mLf;
                float tR = __shfl_down(T[i].x, 1) * mRf;
                float mR_ = __shfl_down(M[i].x, 1) * mRf;
                float bR = __shfl_down(B[i].x, 1) * mRf;
                float o0 = w0 * tL     + w1 * T[i].x + w2 * T[i].y
                         + w3 * mL_    + w4 * M[i].x + w5 * M[i].y
                         + w6 * bL     + w7 * B[i].x + w8 * B[i].y;
                float o1 = w0 * T[i].x + w1 * T[i].y + w2 * tR
                         + w3 * M[i].x + w4 * M[i].y + w5 * mR_
                         + w6 * B[i].x + w7 * B[i].y + w8 * bR;
                int cl = cl0 + i;
                dst[0][2 * lane][cl]     = f2bf(M[i].x);
                dst[0][2 * lane + 1][cl] = f2bf(M[i].y);
                dst[1][2 * lane][cl]     = f2bf(o0);
                dst[1][2 * lane + 1][cl] = f2bf(o1);
            }
        }
        __syncthreads();
        #pragma unroll
        for (int T2 = 0; T2 < 2; ++T2) {
            u16* gp = T2 ? dwT : fmapT;
            #pragma unroll
            for (int it = 0; it < 4; ++it) {
                int u = it * 256 + t;
                int y = u >> 3, c8 = (u & 7) * 8;
                const u16* s = &dst[T2][y][c8];
                uint4 val;
                val.x = *(const u32*)(s);
                val.y = *(const u32*)(s + 2);
                val.z = *(const u32*)(s + 4);
                val.w = *(const u32*)(s + 6);
                *(uint4*)(gp + (nbase + y) * 256 + chunk * 64 + c8) = val;
            }
        }
        __syncthreads();
    }
}

// ---------------- K2+K3 fused: kv projection + exp + context + denom ----------------
// Double-buffered ping-pong staging (T14 issue-early): loads for kc+1 issue
// BEFORE the MFMAs on kc; ds_write after (vmcnt wait lands post-MFMA).
// LDS 64KB: A0/A1 (weights dbuf), B0/B1 (pixel dbuf), EL/VL alias A0/A1.
// XOR granule swizzle (g ^= row&7) on both sides, unpadded stride ->
// uniform bank distribution at the b128 8-cycle floor.
__global__ __launch_bounds__(256, 2) void k_kvctx(
    const u16* __restrict__ dwT, const u16* __restrict__ wpw,
    float* __restrict__ ctx, float* __restrict__ denom)
{
    const int t = threadIdx.x;
    const int lane = t & 63, w = t >> 6;
    const int l15 = lane & 15, quad = lane >> 4;

    // XCD-chunked swizzle (1024 blocks, 8 XCDs -> 128-block contiguous chunks)
    const int L = blockIdx.x;
    const int work = (L & 7) * 128 + (L >> 3);
    const int s = work >> 6;          // slice 0..15
    const int b = (work >> 3) & 7;    // batch
    const int h = work & 7;           // head
    const int bh = b * 8 + h;

    __shared__ __align__(16) u16 sm[32768];  // 64 KB
    // regions (u16 offsets): A0=0, A1=8192, B0=16384, B1=24576
    u16* EL = sm;          // [64 ch][128 px] swizzled, aliases A0
    u16* VL = sm + 8192;   // aliases A1

    const int ph = (w & 1) * 64;      // pixel half owned by this wave (GEMM)
    const int ck = (w >> 1);          // 0 = k-channels half, 1 = v-channels half

    const int srow = t >> 3;          // staging row 0..31 (+32p)
    const int sg = t & 7;             // staging granule

    f32x4 ctxacc[4] = {};
    float dpart[4] = {0.f, 0.f, 0.f, 0.f};

    uint4 ra[4], rb[4];

#define KV_STAGE_LOAD(stv, kcv)                                                        \
    {                                                                                  \
        const u16* xr = dwT + ((size_t)b * NPIX + s * 1024 + (stv) * 128) * 256;       \
        _Pragma("unroll")                                                              \
        for (int p = 0; p < 4; ++p) {                                                  \
            int row = srow + 32 * p;                                                   \
            int wr = (row < 64) ? (h * 64 + row) : (512 + h * 64 + (row - 64));        \
            ra[p] = *(const uint4*)(wpw + (size_t)wr * 256 + (kcv) * 64 + sg * 8);     \
            rb[p] = *(const uint4*)(xr + (size_t)row * 256 + (kcv) * 64 + sg * 8);     \
        }                                                                              \
    }

#define KV_STAGE_WRITE(bufi)                                                           \
    {                                                                                  \
        u16* Ad = sm + (bufi) * 8192;                                                  \
        u16* Bd = sm + 16384 + (bufi) * 8192;                                          \
        _Pragma("unroll")                                                              \
        for (int p = 0; p < 4; ++p) {                                                  \
            int row = srow + 32 * p;                                                   \
            int off = row * 64 + ((sg ^ (row & 7)) << 3);                              \
            *(uint4*)(Ad + off) = ra[p];                                               \
            *(uint4*)(Bd + off) = rb[p];                                               \
        }                                                                              \
    }

    KV_STAGE_LOAD(0, 0);   // prologue: st=0, kc=0

    for (int st = 0; st < 8; ++st) {
        KV_STAGE_WRITE(0);
        __syncthreads();
        f32x4 acc[4][4] = {};
        #pragma unroll
        for (int kc = 0; kc < 4; ++kc) {
            if (kc < 3) KV_STAGE_LOAD(st, kc + 1);
            {
                const u16* Ax = sm + (kc & 1) * 8192;
                const u16* Bx = sm + 16384 + (kc & 1) * 8192;
                #pragma unroll
                for (int kk = 0; kk < 64; kk += 32) {
                    bf16x8 av[4], bv[4];
                    #pragma unroll
                    for (int mf = 0; mf < 4; ++mf) {
                        int pr = ph + mf * 16 + l15;
                        int pg = ((kk >> 3) + quad) ^ (pr & 7);
                        av[mf] = *(const bf16x8*)(Bx + pr * 64 + (pg << 3));
                    }
                    #pragma unroll
                    for (int nf = 0; nf < 4; ++nf) {
                        int wr2 = ck * 64 + nf * 16 + l15;
                        int wg = ((kk >> 3) + quad) ^ (wr2 & 7);
                        bv[nf] = *(const bf16x8*)(Ax + wr2 * 64 + (wg << 3));
                    }
                    #pragma unroll
                    for (int mf = 0; mf < 4; ++mf)
                        #pragma unroll
                        for (int nf = 0; nf < 4; ++nf)
                            acc[mf][nf] = __builtin_amdgcn_mfma_f32_16x16x32_bf16(av[mf], bv[nf], acc[mf][nf], 0, 0, 0);
                }
            }
            if (kc < 3) {
                KV_STAGE_WRITE((kc + 1) & 1);
                __syncthreads();
            }
        }
        __syncthreads();   // all GEMM reads done before EL/VL (A0/A1) overwrite
        // epilogue: acc rows = pixels, cols = channels; write 4 px / 8B, swizzled.
        u16* dst = ck ? VL : EL;
        #pragma unroll
        for (int nf = 0; nf < 4; ++nf) {
            const int ch = nf * 16 + l15;
            const int key = ch & 7;
            float colsum = 0.f;
            #pragma unroll
            for (int mf = 0; mf < 4; ++mf) {
                const int c = ph + mf * 16 + quad * 4;
                float v0 = acc[mf][nf][0], v1 = acc[mf][nf][1];
                float v2 = acc[mf][nf][2], v3 = acc[mf][nf][3];
                if (ck == 0) {
                    v0 = __expf(v0); v1 = __expf(v1);
                    v2 = __expf(v2); v3 = __expf(v3);
                    colsum += (v0 + v1) + (v2 + v3);
                }
                uint2 u; u.x = pk2(v0, v1); u.y = pk2(v2, v3);
                int addr = ch * 128 + ((((c >> 3) ^ key)) << 3) + (c & 7);
                *(uint2*)(dst + addr) = u;
            }
            if (ck == 0) {
                colsum += __shfl_xor(colsum, 16);
                colsum += __shfl_xor(colsum, 32);
                dpart[nf] += colsum;
            }
        }
        if (st < 7) KV_STAGE_LOAD(st + 1, 0);   // prefetch next subtile (overlaps ctx)
        __syncthreads();
        // ctx accumulation: wave w owns e-rows [w*16, w*16+16)
        #pragma unroll
        for (int kk2 = 0; kk2 < 128; kk2 += 32) {
            int ar = w * 16 + l15;
            int ag = ((kk2 >> 3) + quad) ^ (ar & 7);
            bf16x8 av = *(const bf16x8*)(VL + ar * 128 + (ag << 3));
            #pragma unroll
            for (int nf = 0; nf < 4; ++nf) {
                int br = nf * 16 + l15;
                int bg = ((kk2 >> 3) + quad) ^ (br & 7);
                bf16x8 bv = *(const bf16x8*)(EL + br * 128 + (bg << 3));
                ctxacc[nf] = __builtin_amdgcn_mfma_f32_16x16x32_bf16(av, bv, ctxacc[nf], 0, 0, 0);
            }
        }
        __syncthreads();   // ctx reads done before next subtile's staging write
    }
    // finale: one atomic pass
    #pragma unroll
    for (int nf = 0; nf < 4; ++nf)
        #pragma unroll
        for (int r = 0; r < 4; ++r) {
            int e = w * 16 + quad * 4 + r;
            int d = nf * 16 + l15;
            atomicAdd(ctx + ((size_t)bh * 64 + e) * 64 + d, ctxacc[nf][r]);
        }
    if (ck == 0 && quad == 0) {
        #pragma unroll
        for (int nf = 0; nf < 4; ++nf)
            atomicAdd(denom + bh * 64 + nf * 16 + l15, dpart[nf]);
    }
#undef KV_STAGE_LOAD
#undef KV_STAGE_WRITE
}

// ---------------- K1: q projection GEMM + fused per-(pixel,head) softmax * 1/8 ----------------
// Same ping-pong / issue-early restructure as k_kvctx.
__global__ __launch_bounds__(256) void k_proj_q(
    const u16* __restrict__ fmapT, const u16* __restrict__ wq,
    u16* __restrict__ q)
{
    const int t = threadIdx.x;
    const int lane = t & 63, w = t >> 6;
    const int l15 = lane & 15, quad = lane >> 4;
    const int n0 = blockIdx.x * 128;
    const int o0 = blockIdx.y * 128;
    const int b  = blockIdx.z;
    __shared__ __align__(16) unsigned char smraw[71680];
    u16* sm16 = (u16*)smraw;   // A0=0, A1=8192, B0=16384, B1=24576 (u16 offsets)
    f32x4 acc[4][4] = {};
    const int mh = (w >> 1) * 64, nh = (w & 1) * 64;
    const u16* wrow = wq + (size_t)o0 * 256;
    const u16* xrow = fmapT + ((size_t)b * NPIX + n0) * 256;
    const int srow = t >> 3;
    const int sg = t & 7;
    uint4 ra[4], rb[4];

#define Q_STAGE_LOAD(kcv)                                                              \
    {                                                                                  \
        _Pragma("unroll")                                                              \
        for (int p = 0; p < 4; ++p) {                                                  \
            int row = srow + 32 * p;                                                   \
            ra[p] = *(const uint4*)(wrow + (size_t)row * 256 + (kcv) * 64 + sg * 8);   \
            rb[p] = *(const uint4*)(xrow + (size_t)row * 256 + (kcv) * 64 + sg * 8);   \
        }                                                                              \
    }

#define Q_STAGE_WRITE(bufi)                                                            \
    {                                                                                  \
        u16* Ad = sm16 + (bufi) * 8192;                                                \
        u16* Bd = sm16 + 16384 + (bufi) * 8192;                                        \
        _Pragma("unroll")                                                              \
        for (int p = 0; p < 4; ++p) {                                                  \
            int row = srow + 32 * p;                                                   \
            int off = row * 64 + ((sg ^ (row & 7)) << 3);                              \
            *(uint4*)(Ad + off) = ra[p];                                               \
            *(uint4*)(Bd + off) = rb[p];                                               \
        }                                                                              \
    }

    Q_STAGE_LOAD(0);
    Q_STAGE_WRITE(0);
    __syncthreads();
    #pragma unroll
    for (int kc = 0; kc < 4; ++kc) {
        if (kc < 3) Q_STAGE_LOAD(kc + 1);
        {
            const u16* Ax = sm16 + (kc & 1) * 8192;
            const u16* Bx = sm16 + 16384 + (kc & 1) * 8192;
            #pragma unroll
            for (int kk = 0; kk < 64; kk += 32) {
                bf16x8 av[4], bv[4];
                #pragma unroll
                for (int mf = 0; mf < 4; ++mf) {
                    int arow = mh + mf * 16 + l15;
                    int agr = ((kk >> 3) + quad) ^ (arow & 7);
                    av[mf] = *(const bf16x8*)(Ax + arow * 64 + (agr << 3));
                }
                #pragma unroll
                for (int nf = 0; nf < 4; ++nf) {
                    int brow = nh + nf * 16 + l15;
                    int bgr = ((kk >> 3) + quad) ^ (brow & 7);
                    bv[nf] = *(const bf16x8*)(Bx + brow * 64 + (bgr << 3));
                }
                #pragma unroll
                for (int mf = 0; mf < 4; ++mf)
                    #pragma unroll
                    for (int nf = 0; nf < 4; ++nf)
                        acc[mf][nf] = __builtin_amdgcn_mfma_f32_16x16x32_bf16(av[mf], bv[nf], acc[mf][nf], 0, 0, 0);
            }
        }
        if (kc < 3) {
            Q_STAGE_WRITE((kc + 1) & 1);
            __syncthreads();
        }
    }
    __syncthreads();
    float* ep = (float*)smraw;  // [128 pix][140] fp32 logits, transposed
    #pragma unroll
    for (int mf = 0; mf < 4; ++mf)
        #pragma unroll
        for (int nf = 0; nf < 4; ++nf)
            #pragma unroll
            for (int r = 0; r < 4; ++r) {
                int row = mh + mf * 16 + quad * 4 + r;  // local channel 0..127
                int col = nh + nf * 16 + l15;           // pixel
                ep[col * 140 + row] = acc[mf][nf][r];
            }
    __syncthreads();
    const int h0 = blockIdx.y * 2;
    for (int p = 0; p < 8; ++p) {
        int unit = p * 32 + (t >> 3);
        int pix = unit >> 1, hh = unit & 1;
        int d8 = (t & 7) * 8;
        f32x4 v0 = *(const f32x4*)(ep + pix * 140 + hh * 64 + d8);
        f32x4 v1 = *(const f32x4*)(ep + pix * 140 + hh * 64 + d8 + 4);
        float e0 = __expf(v0[0]), e1 = __expf(v0[1]), e2 = __expf(v0[2]), e3 = __expf(v0[3]);
        float e4 = __expf(v1[0]), e5 = __expf(v1[1]), e6 = __expf(v1[2]), e7 = __expf(v1[3]);
        float s = ((e0 + e1) + (e2 + e3)) + ((e4 + e5) + (e6 + e7));
        s += __shfl_xor(s, 1); s += __shfl_xor(s, 2); s += __shfl_xor(s, 4);
        float r = 0.125f / s;
        uint4 u;
        u.x = pk2(e0 * r, e1 * r); u.y = pk2(e2 * r, e3 * r);
        u.z = pk2(e4 * r, e5 * r); u.w = pk2(e6 * r, e7 * r);
        size_t off = (((size_t)b * 8 + h0 + hh) * NPIX + n0 + pix) * 64 + d8;
        *(uint4*)(q + off) = u;
    }
#undef Q_STAGE_LOAD
#undef Q_STAGE_WRITE
}

// ---------------- K4: out = (gelu(q @ ctx_norm)) @ w_out^T + b ----------------
__global__ __launch_bounds__(256) void k_attnout(
    const u16* __restrict__ q, const float* __restrict__ ctx,
    const float* __restrict__ denom, const u16* __restrict__ wout,
    const float* __restrict__ bout, float* __restrict__ out)
{
    const int t = threadIdx.x;
    const int lane = t & 63, w = t >> 6;
    const int l15 = lane & 15, quad = lane >> 4;
    const int n0 = blockIdx.x * 32;
    const int b  = blockIdx.y;
    __shared__ __align__(16) u16 tmp[32 * 520];
    __shared__ __align__(16) unsigned char R[20480];
    u16* qs = (u16*)R;            // [32][72]
    u16* cs = (u16*)(R + 4608);   // [64][72]
    u16* ws = (u16*)R;            // [256][40] (reused after head loop)
    for (int h = 0; h < 8; ++h) {
        __syncthreads();
        {
            int row = t >> 3, g = t & 7;
            *(uint4*)(qs + row * 72 + g * 8) =
                *(const uint4*)(q + (((size_t)b * 8 + h) * NPIX + n0 + row) * 64 + g * 8);
        }
        const int bh = b * 8 + h;
        #pragma unroll
        for (int p = 0; p < 4; ++p) {
            int idx = p * 256 + t;
            int e = idx >> 4, dq = (idx & 15) * 4;
            f32x4 c4 = *(const f32x4*)(ctx + ((size_t)bh * 64 + e) * 64 + dq);
            f32x4 d4 = *(const f32x4*)(denom + bh * 64 + dq);
            uint2 u;
            u.x = pk2(c4[0] / d4[0], c4[1] / d4[1]);
            u.y = pk2(c4[2] / d4[2], c4[3] / d4[3]);
            *(uint2*)(cs + e * 72 + dq) = u;
        }
        __syncthreads();
        f32x4 a1[2] = {};
        #pragma unroll
        for (int kk = 0; kk < 64; kk += 32) {
            bf16x8 av = *(const bf16x8*)(qs + ((w & 1) * 16 + l15) * 72 + kk + quad * 8);
            #pragma unroll
            for (int j = 0; j < 2; ++j) {
                int nf = (w >> 1) * 2 + j;
                bf16x8 bv = *(const bf16x8*)(cs + (nf * 16 + l15) * 72 + kk + quad * 8);
                a1[j] = __builtin_amdgcn_mfma_f32_16x16x32_bf16(av, bv, a1[j], 0, 0, 0);
            }
        }
        #pragma unroll
        for (int j = 0; j < 2; ++j)
            #pragma unroll
            for (int r = 0; r < 4; ++r) {
                int pix = (w & 1) * 16 + quad * 4 + r;
                int e = ((w >> 1) * 2 + j) * 16 + l15;
                float x = a1[j][r];
                float gel = 0.5f * x * (1.0f + erff(x * 0.70710678118654752f));
                tmp[pix * 520 + h * 64 + e] = f2bf(gel);
            }
    }
    __syncthreads();
    f32x4 acc[4][2] = {};
    for (int kc = 0; kc < 16; ++kc) {
        __syncthreads();
        #pragma unroll
        for (int p = 0; p < 4; ++p) {
            int c = (t >> 2) + 64 * p, g = t & 3;
            *(uint4*)(ws + c * 40 + g * 8) = *(const uint4*)(wout + (size_t)c * 512 + kc * 32 + g * 8);
        }
        __syncthreads();
        bf16x8 av[4], bv[2];
        #pragma unroll
        for (int mf = 0; mf < 4; ++mf)
            av[mf] = *(const bf16x8*)(ws + (w * 64 + mf * 16 + l15) * 40 + quad * 8);
        #pragma unroll
        for (int nf = 0; nf < 2; ++nf)
            bv[nf] = *(const bf16x8*)(tmp + (nf * 16 + l15) * 520 + kc * 32 + quad * 8);
        #pragma unroll
        for (int mf = 0; mf < 4; ++mf)
            #pragma unroll
            for (int nf = 0; nf < 2; ++nf)
                acc[mf][nf] = __builtin_amdgcn_mfma_f32_16x16x32_bf16(av[mf], bv[nf], acc[mf][nf], 0, 0, 0);
    }
    #pragma unroll
    for (int mf = 0; mf < 4; ++mf)
        #pragma unroll
        for (int nf = 0; nf < 2; ++nf)
            #pragma unroll
            for (int r = 0; r < 4; ++r) {
                int c = w * 64 + mf * 16 + quad * 4 + r;
                int pix = nf * 16 + l15;
                out[((size_t)b * 256 + c) * NPIX + n0 + pix] = acc[mf][nf][r] + bout[c];
            }
}

extern "C" void kernel_launch(void* const* d_in, const int* in_sizes, int n_in,
                              void* d_out, int out_size, void* d_ws, size_t ws_size,
                              hipStream_t stream)
{
    const float* fmap  = (const float*)d_in[0];
    const float* w_q   = (const float*)d_in[1];
    const float* w_dw  = (const float*)d_in[2];
    const float* w_pw  = (const float*)d_in[3];
    const float* w_out = (const float*)d_in[4];
    const float* b_out = (const float*)d_in[5];
    float* out = (float*)d_out;
    char* ws = (char*)d_ws;

    u16* dwT     = (u16*)(ws);                  // 67,108,864 B  [8][16384][256]
    u16* fmapT   = (u16*)(ws + 67108864);       // 67,108,864 B
    u16* q       = (u16*)(ws + 134217728);      // 134,217,728 B
    float* ctx   = (float*)(ws + 402653184);    // 1,048,576 B  [64][64][64]
    float* denom = (float*)(ws + 403701760);    // 16,384 B
    u16* wq_b    = (u16*)(ws + 403718144);      // 262,144 B
    u16* wpw_b   = (u16*)(ws + 403980288);      // 524,288 B
    u16* wout_b  = (u16*)(ws + 404504576);      // 262,144 B
    // total workspace: 404,766,720 B

    hipMemsetAsync(ws + 402653184, 0, 1048576 + 16384, stream);
    k_cvtw<<<512, 256, 0, stream>>>(w_q, w_pw, w_out, wq_b, wpw_b, wout_b);
    k_conv<<<dim3(128, 8), 256, 0, stream>>>(fmap, w_dw, fmapT, dwT);
    k_kvctx<<<1024, 256, 0, stream>>>(dwT, wpw_b, ctx, denom);
    k_proj_q<<<dim3(128, 4, 8), 256, 0, stream>>>(fmapT, wq_b, q);
    k_attnout<<<dim3(512, 8), 256, 0, stream>>>(q, ctx, denom, wout_b, b_out, out);
}